// Round 15
// baseline (42.751 us; speedup 1.0000x reference)
//
#include <hip/hip_runtime.h>

// QuantumAttention: out[b,s,e] = sum_q q[b,s,q] * W_dec[e,q] + x[b,s,e]
//   angles = x @ W_enc^T, c = cos(angles)
//   q[0] = prod(c[1..7]); q[i] = prod(c[0..i])
//
// R15 = R9 (best, 30.7us) + maximum async read depth:
//  - ALL 8 tokens' x staged at block start via global_load_lds (cannot be
//    sunk by the allocator, zero VGPR) into 32KB LDS, wave-private quarters.
//  - weights issued FIRST, sched_barrier, then stages; token i consumed
//    behind counted vmcnt(7-i) (never 0 mid-kernel).
//  - raw s_barrier + lgkmcnt only (no vmcnt drain at barriers).
//  - rest is R9 verbatim: DPP wave_sum63, wave0 cos+cumprod DPP scan,
//    dedup decode with broadcast qv reads, plain v4f stores.

typedef float v2f __attribute__((ext_vector_type(2)));
typedef float v4f __attribute__((ext_vector_type(4)));

#define EDIM 1024
#define QDIM 8
#define NTOK 16384
#define BLOCK 256
#define T 8
#define GRID (NTOK / T)   // 2048

#define GLOAD_LDS(gsrc, ldst)                                                  \
    __builtin_amdgcn_global_load_lds(                                          \
        (const __attribute__((address_space(1))) void*)(gsrc),                 \
        (__attribute__((address_space(3))) void*)(ldst), 16, 0, 0)

template<int CTRL>
__device__ __forceinline__ float dpp_add(float v) {
    int m = __builtin_amdgcn_update_dpp(0, __float_as_int(v), CTRL, 0xF, 0xF, true);
    return v + __int_as_float(m);
}

// 64-lane sum on the VALU pipe; result valid in lane 63 only.
__device__ __forceinline__ float wave_sum63(float v) {
    v = dpp_add<0x111>(v);   // row_shr:1
    v = dpp_add<0x112>(v);   // row_shr:2
    v = dpp_add<0x114>(v);   // row_shr:4
    v = dpp_add<0x118>(v);   // row_shr:8
    v = dpp_add<0x142>(v);   // row_bcast:15
    v = dpp_add<0x143>(v);   // row_bcast:31
    return v;
}

// inclusive product-scan step within 8-lane groups (guarded row_shr)
template<int K>
__device__ __forceinline__ float scan_mul_step(float p, int laneq) {
    int m = __builtin_amdgcn_update_dpp(0, __float_as_int(p), 0x110 | K, 0xF, 0xF, true);
    float tmul = (laneq >= K) ? __int_as_float(m) : 1.0f;
    return p * tmul;
}

__global__ __launch_bounds__(BLOCK, 4)
void qattn_kernel(const float* __restrict__ x,
                  const float* __restrict__ W_enc,   // [Q][E]
                  const float* __restrict__ W_dec,   // [E][Q]
                  float* __restrict__ out)
{
    __shared__ float xbuf[T][4][256];   // 32 KB: [tok][wave][elem-in-quarter]
    __shared__ float red[T][4][QDIM];
    __shared__ float qv_s[T][QDIM];

    const int t    = threadIdx.x;
    const int lane = t & 63;
    const int wave = t >> 6;
    const int e0   = t * 4;             // = wave*256 + lane*4
    const int tok0 = blockIdx.x * T;

    // ---- 1. weight loads FIRST (oldest VMEM; 16 instrs) ----
    v4f wenc[QDIM];
#pragma unroll
    for (int q = 0; q < QDIM; ++q)
        wenc[q] = *(const v4f*)(W_enc + q * EDIM + e0);
    v4f wdlo[4], wdhi[4];
#pragma unroll
    for (int j = 0; j < 4; ++j) {
        wdlo[j] = *(const v4f*)(W_dec + (e0 + j) * QDIM);
        wdhi[j] = *(const v4f*)(W_dec + (e0 + j) * QDIM + 4);
    }
    __builtin_amdgcn_sched_barrier(0);

    // ---- 2. stage ALL 8 tokens' x (8 gload_lds/wave, in token order) ----
#pragma unroll
    for (int i = 0; i < T; ++i) {
        const float* src = x + (size_t)(tok0 + i) * EDIM + wave * 256 + lane * 4;
        GLOAD_LDS(src, &xbuf[i][wave][0]);
    }
    __builtin_amdgcn_sched_barrier(0);

    // ---- 3. encode in 2 halves of 4 tokens; counted vmcnt per token ----
#pragma unroll
    for (int h = 0; h < 2; ++h) {
        float ang[4][QDIM];
#pragma unroll
        for (int i = 0; i < 4; ++i) {
            const int ii = h * 4 + i;
            // stages were issued in token order AFTER the 16 weight loads:
            // waiting to <= (7-ii) outstanding completes weights + stages 0..ii
            switch (ii) {
                case 0: asm volatile("s_waitcnt vmcnt(7)" ::: "memory"); break;
                case 1: asm volatile("s_waitcnt vmcnt(6)" ::: "memory"); break;
                case 2: asm volatile("s_waitcnt vmcnt(5)" ::: "memory"); break;
                case 3: asm volatile("s_waitcnt vmcnt(4)" ::: "memory"); break;
                case 4: asm volatile("s_waitcnt vmcnt(3)" ::: "memory"); break;
                case 5: asm volatile("s_waitcnt vmcnt(2)" ::: "memory"); break;
                case 6: asm volatile("s_waitcnt vmcnt(1)" ::: "memory"); break;
                case 7: asm volatile("s_waitcnt vmcnt(0)" ::: "memory"); break;
            }
            __builtin_amdgcn_sched_barrier(0);
            v4f xv = *(const v4f*)&xbuf[ii][wave][lane * 4];
            v2f x01 = (v2f){xv.x, xv.y};
            v2f x23 = (v2f){xv.z, xv.w};
#pragma unroll
            for (int q = 0; q < QDIM; ++q) {
                v2f acc = x01 * (v2f){wenc[q].x, wenc[q].y};
                acc = __builtin_elementwise_fma(x23, (v2f){wenc[q].z, wenc[q].w}, acc);
                ang[i][q] = acc.x + acc.y;
            }
        }
#pragma unroll
        for (int i = 0; i < 4; ++i)
#pragma unroll
            for (int q = 0; q < QDIM; ++q)
                ang[i][q] = wave_sum63(ang[i][q]);

        if (lane == 63) {
#pragma unroll
            for (int i = 0; i < 4; ++i) {
                *(v4f*)&red[h * 4 + i][wave][0] =
                    (v4f){ang[i][0], ang[i][1], ang[i][2], ang[i][3]};
                *(v4f*)&red[h * 4 + i][wave][4] =
                    (v4f){ang[i][4], ang[i][5], ang[i][6], ang[i][7]};
            }
        }
    }

    // ---- 4. barrier (LDS only, no vmcnt drain) ----
    asm volatile("s_waitcnt lgkmcnt(0)" ::: "memory");
    __builtin_amdgcn_s_barrier();
    __builtin_amdgcn_sched_barrier(0);

    // ---- 5. wave 0: combine + cos + cumprod scan (lanes 0..63 = 8tok x 8q) ----
    if (wave == 0) {
        const int tk = lane >> 3;
        const int q  = lane & 7;
        float s = red[tk][0][q] + red[tk][1][q] + red[tk][2][q] + red[tk][3][q];
        float c = __cosf(s);

        float p = c;                      // q -> c0*...*cq
        p = scan_mul_step<1>(p, q);
        p = scan_mul_step<2>(p, q);
        p = scan_mul_step<4>(p, q);

        float b = (q == 0) ? 1.0f : c;    // q=7 -> c1*...*c7
        b = scan_mul_step<1>(b, q);
        b = scan_mul_step<2>(b, q);
        b = scan_mul_step<4>(b, q);

        if (q > 0)  qv_s[tk][q] = p;
        if (q == 7) qv_s[tk][0] = b;
    }

    // ---- 6. barrier (LDS only) ----
    asm volatile("s_waitcnt lgkmcnt(0)" ::: "memory");
    __builtin_amdgcn_s_barrier();
    __builtin_amdgcn_sched_barrier(0);

    // ---- 7. decode + residual (x re-read from LDS) + store ----
#pragma unroll
    for (int i = 0; i < T; ++i) {
        v4f qlo = *(const v4f*)&qv_s[i][0];
        v4f qhi = *(const v4f*)&qv_s[i][4];
        v4f xv  = *(const v4f*)&xbuf[i][wave][lane * 4];
        float od[4];
#pragma unroll
        for (int j = 0; j < 4; ++j) {
            v2f a = __builtin_elementwise_fma(
                        (v2f){qlo.x, qlo.y}, (v2f){wdlo[j].x, wdlo[j].y},
                        (v2f){xv[j], 0.f});
            a = __builtin_elementwise_fma((v2f){qlo.z, qlo.w},
                                          (v2f){wdlo[j].z, wdlo[j].w}, a);
            a = __builtin_elementwise_fma((v2f){qhi.x, qhi.y},
                                          (v2f){wdhi[j].x, wdhi[j].y}, a);
            a = __builtin_elementwise_fma((v2f){qhi.z, qhi.w},
                                          (v2f){wdhi[j].z, wdhi[j].w}, a);
            od[j] = a.x + a.y;
        }
        *(v4f*)(out + (size_t)(tok0 + i) * EDIM + e0) =
            (v4f){od[0], od[1], od[2], od[3]};
    }
}

extern "C" void kernel_launch(void* const* d_in, const int* in_sizes, int n_in,
                              void* d_out, int out_size, void* d_ws, size_t ws_size,
                              hipStream_t stream) {
    const float* x     = (const float*)d_in[0];
    const float* W_enc = (const float*)d_in[1];
    const float* W_dec = (const float*)d_in[2];
    float* out         = (float*)d_out;
    (void)d_ws; (void)ws_size;

    hipLaunchKernelGGL(qattn_kernel, dim3(GRID), dim3(BLOCK), 0, stream,
                       x, W_enc, W_dec, out);
}

// Round 16
// 37.984 us; speedup vs baseline: 1.1255x; 1.1255x over previous
//
#include <hip/hip_runtime.h>
#include <hip/hip_bf16.h>

// QuantumAttention: out[b,s,e] = sum_q q[b,s,q] * W_dec[e,q] + x[b,s,e]
//   angles = x @ W_enc^T, c = cos(angles)
//   q[0] = prod(c[1..7]); q[i] = prod(c[0..i])
//
// R16 = R9 geometry (grid 2048, T=8, 4 waves, dedup combine, NT stores)
// with the encode+DPP-reduce (72 of ~104 VALU instrs/wave/token) replaced
// by MFMA: each wave computes the block's 16x16 angle tile on its own
// K=256 slice (8 x mfma_f32_16x16x32_bf16), A/B fragments loaded DIRECTLY
// from global (per-lane 32B; each 128B line fully consumed over the kk
// loop -> no over-fetch; W_enc slice L1/L2-resident). C partials summed
// cross-wave via red2[tok][col][wave] (one ds_read_b128 per (tok,q)).
// Fragment layouts are R13/R14-validated (absmax 0.031 at same precision).

typedef float v2f __attribute__((ext_vector_type(2)));
typedef float v4f __attribute__((ext_vector_type(4)));
typedef short bf16x8 __attribute__((ext_vector_type(8)));

#define EDIM 1024
#define QDIM 8
#define NTOK 16384
#define BLOCK 256
#define T 8
#define GRID (NTOK / T)   // 2048

__device__ __forceinline__ short f2bf(float f) {
    __hip_bfloat16 h = __float2bfloat16(f);
    return *reinterpret_cast<short*>(&h);
}

// inclusive product-scan step within 8-lane groups (guarded row_shr)
template<int K>
__device__ __forceinline__ float scan_mul_step(float p, int laneq) {
    int m = __builtin_amdgcn_update_dpp(0, __float_as_int(p), 0x110 | K, 0xF, 0xF, true);
    float tmul = (laneq >= K) ? __int_as_float(m) : 1.0f;
    return p * tmul;
}

__global__ __launch_bounds__(BLOCK, 2)
void qattn_kernel(const float* __restrict__ x,
                  const float* __restrict__ W_enc,   // [Q][E]
                  const float* __restrict__ W_dec,   // [E][Q]
                  float* __restrict__ out)
{
    __shared__ float red2[T][16][4];   // [tok-row][col][wave] = 2 KB
    __shared__ float qv_s[T][QDIM];    // 256 B

    const int t    = threadIdx.x;
    const int lane = t & 63;
    const int wave = t >> 6;
    const int e0   = t * 4;
    const int tok0 = blockIdx.x * T;

    // ---- decode weights in regs (R9) ----
    v4f wdlo[4], wdhi[4];
#pragma unroll
    for (int j = 0; j < 4; ++j) {
        wdlo[j] = *(const v4f*)(W_dec + (e0 + j) * QDIM);
        wdhi[j] = *(const v4f*)(W_dec + (e0 + j) * QDIM + 4);
    }

    // ---- MFMA encode: wave's K=256 slice of the 16x16 angle tile ----
    // A: lane holds x[tok = lane&15][k = (lane>>4)*8 + j]  (rows >= 8: pad 0)
    // B: lane holds W_enc[q = lane&15][same k]             (cols >= 8: pad 0)
    const int r16  = lane & 15;           // A-row / B-col index
    const int kg   = lane >> 4;
    const bool ok  = (r16 < T);           // rows 8-15 and cols 8-15 are pad
    const int koff = wave * 256 + kg * 8;

    v4f acc = (v4f){0.f, 0.f, 0.f, 0.f};
    const float* abase = x + (size_t)(tok0 + r16) * EDIM + koff;
    const float* bbase = W_enc + (size_t)r16 * EDIM + koff;

#pragma unroll
    for (int kk = 0; kk < 8; ++kk) {
        bf16x8 av = (bf16x8){0, 0, 0, 0, 0, 0, 0, 0};
        bf16x8 bv = (bf16x8){0, 0, 0, 0, 0, 0, 0, 0};
        if (ok) {
            v4f a0 = *(const v4f*)(abase + kk * 32);
            v4f a1 = *(const v4f*)(abase + kk * 32 + 4);
            v4f b0 = *(const v4f*)(bbase + kk * 32);
            v4f b1 = *(const v4f*)(bbase + kk * 32 + 4);
            av[0] = f2bf(a0.x); av[1] = f2bf(a0.y);
            av[2] = f2bf(a0.z); av[3] = f2bf(a0.w);
            av[4] = f2bf(a1.x); av[5] = f2bf(a1.y);
            av[6] = f2bf(a1.z); av[7] = f2bf(a1.w);
            bv[0] = f2bf(b0.x); bv[1] = f2bf(b0.y);
            bv[2] = f2bf(b0.z); bv[3] = f2bf(b0.w);
            bv[4] = f2bf(b1.x); bv[5] = f2bf(b1.y);
            bv[6] = f2bf(b1.z); bv[7] = f2bf(b1.w);
        }
        acc = __builtin_amdgcn_mfma_f32_16x16x32_bf16(av, bv, acc, 0, 0, 0);
    }

    // ---- publish C partials: lane holds D[row=(lane>>4)*4+r][col=lane&15] ----
    // only rows 0..7 are real (kg < 2); cols 8..15 are zeros (stored anyway)
    if (lane < 32) {
#pragma unroll
        for (int r = 0; r < 4; ++r) {
            const int row = kg * 4 + r;
            red2[row][r16][wave] = acc[r];
        }
    }

    asm volatile("s_waitcnt lgkmcnt(0)" ::: "memory");
    __builtin_amdgcn_s_barrier();
    __builtin_amdgcn_sched_barrier(0);

    // ---- wave 0: sum 4 wave-partials, cos, cumprod scan (R9 pattern) ----
    if (wave == 0) {
        const int tk = lane >> 3;
        const int q  = lane & 7;
        v4f w4 = *(const v4f*)&red2[tk][q][0];
        float s = (w4.x + w4.y) + (w4.z + w4.w);
        float c = __cosf(s);

        float p = c;                      // q -> c0*...*cq
        p = scan_mul_step<1>(p, q);
        p = scan_mul_step<2>(p, q);
        p = scan_mul_step<4>(p, q);

        float b = (q == 0) ? 1.0f : c;    // q=7 -> c1*...*c7
        b = scan_mul_step<1>(b, q);
        b = scan_mul_step<2>(b, q);
        b = scan_mul_step<4>(b, q);

        if (q > 0)  qv_s[tk][q] = p;
        if (q == 7) qv_s[tk][0] = b;
    }

    asm volatile("s_waitcnt lgkmcnt(0)" ::: "memory");
    __builtin_amdgcn_s_barrier();
    __builtin_amdgcn_sched_barrier(0);

    // ---- decode + residual (x re-read; block's 32 KB is L1/L2-hot) ----
#pragma unroll
    for (int i = 0; i < T; ++i) {
        v4f qlo = *(const v4f*)&qv_s[i][0];
        v4f qhi = *(const v4f*)&qv_s[i][4];
        v4f xv  = *(const v4f*)(x + (size_t)(tok0 + i) * EDIM + e0);
        float od[4];
#pragma unroll
        for (int j = 0; j < 4; ++j) {
            v2f a = __builtin_elementwise_fma(
                        (v2f){qlo.x, qlo.y}, (v2f){wdlo[j].x, wdlo[j].y},
                        (v2f){xv[j], 0.f});
            a = __builtin_elementwise_fma((v2f){qlo.z, qlo.w},
                                          (v2f){wdlo[j].z, wdlo[j].w}, a);
            a = __builtin_elementwise_fma((v2f){qhi.x, qhi.y},
                                          (v2f){wdhi[j].x, wdhi[j].y}, a);
            a = __builtin_elementwise_fma((v2f){qhi.z, qhi.w},
                                          (v2f){wdhi[j].z, wdhi[j].w}, a);
            od[j] = a.x + a.y;
        }
        v4f o = (v4f){od[0], od[1], od[2], od[3]};
        __builtin_nontemporal_store(o, (v4f*)(out + (size_t)(tok0 + i) * EDIM + e0));
    }
}

extern "C" void kernel_launch(void* const* d_in, const int* in_sizes, int n_in,
                              void* d_out, int out_size, void* d_ws, size_t ws_size,
                              hipStream_t stream) {
    const float* x     = (const float*)d_in[0];
    const float* W_enc = (const float*)d_in[1];
    const float* W_dec = (const float*)d_in[2];
    float* out         = (float*)d_out;
    (void)d_ws; (void)ws_size;

    hipLaunchKernelGGL(qattn_kernel, dim3(GRID), dim3(BLOCK), 0, stream,
                       x, W_enc, W_dec, out);
}

// Round 17
// 30.884 us; speedup vs baseline: 1.3842x; 1.2299x over previous
//
#include <hip/hip_runtime.h>

// QuantumAttention: out[b,s,e] = sum_q q[b,s,q] * W_dec[e,q] + x[b,s,e]
//   angles = x @ W_enc^T, c = cos(angles)
//   q[0] = prod(c[1..7]); q[i] = prod(c[0..i])
//
// R17 = R9 (best, 30.67us) + two targeted fixes:
//  1. launch_bounds(256,4): VGPR<=64 -> 4 blocks/CU resident (R9: ~2.2).
//     Phase-staggered blocks keep SOME block always load-issuing ->
//     continuous aggregate VMEM stream (Little's-law duty-cycle fix).
//  2. red padded [T][4][QDIM+1]: phase-2 read lane=tk*8+q had stride-32
//     -> 8-way bank conflict (measured 49152); stride-36 spreads tk over
//     8 banks -> ~0 conflicts.
// Everything else R9-identical (T=8, grid 2048, DPP reduce, wave0 scan,
// dedup decode, NT stores).

typedef float v2f __attribute__((ext_vector_type(2)));
typedef float v4f __attribute__((ext_vector_type(4)));

#define EDIM 1024
#define QDIM 8
#define NTOK 16384
#define BLOCK 256
#define T 8
#define GRID (NTOK / T)   // 2048

// v += dpp_move(v); bound_ctrl=true -> out-of-range lanes contribute 0
template<int CTRL>
__device__ __forceinline__ float dpp_add(float v) {
    int m = __builtin_amdgcn_update_dpp(0, __float_as_int(v), CTRL, 0xF, 0xF, true);
    return v + __int_as_float(m);
}

// 64-lane sum on the VALU pipe; result valid in lane 63 only.
__device__ __forceinline__ float wave_sum63(float v) {
    v = dpp_add<0x111>(v);   // row_shr:1
    v = dpp_add<0x112>(v);   // row_shr:2
    v = dpp_add<0x114>(v);   // row_shr:4
    v = dpp_add<0x118>(v);   // row_shr:8
    v = dpp_add<0x142>(v);   // row_bcast:15
    v = dpp_add<0x143>(v);   // row_bcast:31
    return v;
}

// inclusive product-scan step within 8-lane groups (guarded row_shr)
template<int K>
__device__ __forceinline__ float scan_mul_step(float p, int laneq) {
    int m = __builtin_amdgcn_update_dpp(0, __float_as_int(p), 0x110 | K, 0xF, 0xF, true);
    float tmul = (laneq >= K) ? __int_as_float(m) : 1.0f;
    return p * tmul;
}

__global__ __launch_bounds__(BLOCK, 4)
void qattn_kernel(const float* __restrict__ x,
                  const float* __restrict__ W_enc,   // [Q][E]
                  const float* __restrict__ W_dec,   // [E][Q]
                  float* __restrict__ out)
{
    __shared__ float red[T][4][QDIM + 1];   // padded: phase-2 reads conflict-free
    __shared__ float qv_s[T][QDIM];

    const int t    = threadIdx.x;
    const int lane = t & 63;
    const int wave = t >> 6;
    const int e0   = t * 4;
    const int tok0 = blockIdx.x * T;

    // ---- all 8 tokens' x up front (independent coalesced v4f loads) ----
    v4f xv[T];
#pragma unroll
    for (int i = 0; i < T; ++i)
        xv[i] = *(const v4f*)(x + (size_t)(tok0 + i) * EDIM + e0);

    v4f wenc[QDIM];
#pragma unroll
    for (int q = 0; q < QDIM; ++q)
        wenc[q] = *(const v4f*)(W_enc + q * EDIM + e0);

    // ---- phase 1: encode + DPP reduce, 2 half-groups (reg pressure) ----
#pragma unroll
    for (int h = 0; h < 2; ++h) {
        float ang[4][QDIM];
#pragma unroll
        for (int i = 0; i < 4; ++i) {
            const int ii = h * 4 + i;
            v2f x01 = (v2f){xv[ii].x, xv[ii].y};
            v2f x23 = (v2f){xv[ii].z, xv[ii].w};
#pragma unroll
            for (int q = 0; q < QDIM; ++q) {
                v2f acc = x01 * (v2f){wenc[q].x, wenc[q].y};
                acc = __builtin_elementwise_fma(x23, (v2f){wenc[q].z, wenc[q].w}, acc);
                ang[i][q] = acc.x + acc.y;
            }
        }
#pragma unroll
        for (int i = 0; i < 4; ++i)
#pragma unroll
            for (int q = 0; q < QDIM; ++q)
                ang[i][q] = wave_sum63(ang[i][q]);

        if (lane == 63) {
#pragma unroll
            for (int i = 0; i < 4; ++i) {
#pragma unroll
                for (int q = 0; q < QDIM; ++q)
                    red[h * 4 + i][wave][q] = ang[i][q];
            }
        }
    }
    __syncthreads();

    // ---- phase 2: wave 0 finishes all 8 tokens (lane = tok*8 + q) ----
    if (wave == 0) {
        const int tk = lane >> 3;
        const int q  = lane & 7;
        float s = red[tk][0][q] + red[tk][1][q] + red[tk][2][q] + red[tk][3][q];
        float c = __cosf(s);

        float p = c;                      // q -> c0*...*cq
        p = scan_mul_step<1>(p, q);
        p = scan_mul_step<2>(p, q);
        p = scan_mul_step<4>(p, q);

        float b = (q == 0) ? 1.0f : c;    // q=7 -> c1*...*c7
        b = scan_mul_step<1>(b, q);
        b = scan_mul_step<2>(b, q);
        b = scan_mul_step<4>(b, q);

        if (q > 0)  qv_s[tk][q] = p;
        if (q == 7) qv_s[tk][0] = b;
    }
    __syncthreads();

    // ---- phase 3: decode + residual (broadcast qv reads) + NT store ----
    v4f wdlo[4], wdhi[4];
#pragma unroll
    for (int j = 0; j < 4; ++j) {
        wdlo[j] = *(const v4f*)(W_dec + (e0 + j) * QDIM);
        wdhi[j] = *(const v4f*)(W_dec + (e0 + j) * QDIM + 4);
    }
#pragma unroll
    for (int i = 0; i < T; ++i) {
        v4f qlo = *(const v4f*)&qv_s[i][0];
        v4f qhi = *(const v4f*)&qv_s[i][4];
        float od[4];
#pragma unroll
        for (int j = 0; j < 4; ++j) {
            v2f a = __builtin_elementwise_fma(
                        (v2f){qlo.x, qlo.y}, (v2f){wdlo[j].x, wdlo[j].y},
                        (v2f){xv[i][j], 0.f});
            a = __builtin_elementwise_fma((v2f){qlo.z, qlo.w},
                                          (v2f){wdlo[j].z, wdlo[j].w}, a);
            a = __builtin_elementwise_fma((v2f){qhi.x, qhi.y},
                                          (v2f){wdhi[j].x, wdhi[j].y}, a);
            a = __builtin_elementwise_fma((v2f){qhi.z, qhi.w},
                                          (v2f){wdhi[j].z, wdhi[j].w}, a);
            od[j] = a.x + a.y;
        }
        v4f o = (v4f){od[0], od[1], od[2], od[3]};
        __builtin_nontemporal_store(o, (v4f*)(out + (size_t)(tok0 + i) * EDIM + e0));
    }
}

extern "C" void kernel_launch(void* const* d_in, const int* in_sizes, int n_in,
                              void* d_out, int out_size, void* d_ws, size_t ws_size,
                              hipStream_t stream) {
    const float* x     = (const float*)d_in[0];
    const float* W_enc = (const float*)d_in[1];
    const float* W_dec = (const float*)d_in[2];
    float* out         = (float*)d_out;
    (void)d_ws; (void)ws_size;

    hipLaunchKernelGGL(qattn_kernel, dim3(GRID), dim3(BLOCK), 0, stream,
                       x, W_enc, W_dec, out);
}